// Round 8
// baseline (156.362 us; speedup 1.0000x reference)
//
#include <hip/hip_runtime.h>
#include <math.h>

// LSH attention: B=2, H=8, S=2048, D=64, 6 bits -> 64 buckets, exact-match.
// Phase 1: bucket codes for Q and K (fused, sign of X.rot)
// Phase 2: one dispatch, 32 blocks:
//          K-blocks: stable counting sort -> k_list
//          Q-blocks: stable counting sort (LDS only) + k-bucket counts (LDS
//          atomics) -> per-wave-group descriptors {q0..q3},{ks|nk<<16}
// Phase 3: wave per 4 same-bucket queries; 2 uniform descriptor loads; 32-key
//          chunks with half-wave D-split scores; no-max softmax; lane=dim PV.

constexpr int S_LEN = 2048;
constexpr int D = 64;
constexpr int NHASH = 6;
constexpr int BH = 16;     // B*H
constexpr int NB = 64;     // 2^NHASH
constexpr int QPAD = 4;    // queries per wave
constexpr int PADQ = S_LEN + (QPAD - 1) * NB;   // 2240
constexpr int NGRP = PADQ / QPAD;               // 560 wave-groups per bh
constexpr int KCH = 32;    // key-chunk width (matches ~32-key buckets)

// ---- Phase 1: bucket codes for Q and K in one dispatch. One wave per vector.
__global__ __launch_bounds__(256) void lsh_buckets2(const float* __restrict__ Q,
                                                    const float* __restrict__ K,
                                                    const float* __restrict__ rot,
                                                    int* __restrict__ qb,
                                                    int* __restrict__ kb) {
    const int gw   = (blockIdx.x * 256 + threadIdx.x) >> 6;
    const int lane = threadIdx.x & 63;
    const bool isK = gw >= BH * S_LEN;
    const int wid  = isK ? gw - BH * S_LEN : gw;
    const float* X = isK ? K : Q;
    int* dst       = isK ? kb : qb;
    const int h    = (wid >> 11) & 7;

    const float x  = X[(size_t)wid * D + lane];
    const float* r = rot + (size_t)h * NHASH * D + lane;
    float p0 = x * r[0 * D], p1 = x * r[1 * D], p2 = x * r[2 * D];
    float p3 = x * r[3 * D], p4 = x * r[4 * D], p5 = x * r[5 * D];
#pragma unroll
    for (int off = 32; off >= 1; off >>= 1) {
        p0 += __shfl_xor(p0, off, 64);
        p1 += __shfl_xor(p1, off, 64);
        p2 += __shfl_xor(p2, off, 64);
        p3 += __shfl_xor(p3, off, 64);
        p4 += __shfl_xor(p4, off, 64);
        p5 += __shfl_xor(p5, off, 64);
    }
    int bucket = (p0 > 0.f ? 1 : 0) | (p1 > 0.f ? 2 : 0) | (p2 > 0.f ? 4 : 0) |
                 (p3 > 0.f ? 8 : 0) | (p4 > 0.f ? 16 : 0) | (p5 > 0.f ? 32 : 0);
    if (lane == 0) dst[wid] = bucket;
}

// ---- Phase 2: one block per (which, bh). which: 0=Q(descriptors) 1=K(list)
__global__ __launch_bounds__(256) void lsh_build_desc(const int* __restrict__ qbuckets,
                                                      const int* __restrict__ kbuckets,
                                                      int* __restrict__ k_list,
                                                      int4* __restrict__ desc_q,
                                                      int* __restrict__ desc_k) {
    __shared__ unsigned short hist[256][NB + 1];
    __shared__ int base[NB + 1];
    __shared__ int qlist[PADQ];        // Q side only
    __shared__ int kcnt[NB], kst[NB];  // Q side only
    const int which = blockIdx.x >> 4;   // 0 = Q, 1 = K
    const int bh    = blockIdx.x & 15;
    const int tid   = threadIdx.x;
    const int* src  = (which ? kbuckets : qbuckets) + bh * S_LEN;

    for (int b = 0; b <= NB; ++b) hist[tid][b] = 0;
    if (!which) {
        for (int t = tid; t < PADQ; t += 256) qlist[t] = -1;
        if (tid < NB) kcnt[tid] = 0;
        __syncthreads();   // kcnt zeroed before LDS atomics
        const int* kb = kbuckets + bh * S_LEN;
#pragma unroll
        for (int i = 0; i < 8; ++i)
            atomicAdd(&kcnt[kb[tid * 8 + i]], 1);
    }

    int myb[8];
#pragma unroll
    for (int i = 0; i < 8; ++i) {
        int b = src[tid * 8 + i];
        myb[i] = b;
        hist[tid][b]++;
    }
    __syncthreads();

    // per-bucket exclusive prefix over chunks -> hist becomes WITHIN-BUCKET offset
    if (tid < NB) {
        int run = 0;
        for (int c = 0; c < 256; ++c) {
            int t = hist[c][tid];
            hist[c][tid] = (unsigned short)run;
            run += t;
        }
        base[tid] = run;   // bucket count
    }
    __syncthreads();

    if (tid == 0) {
        int run = 0;
        if (which) {
            for (int b = 0; b < NB; ++b) {
                int t = base[b];
                base[b] = run;
                run += t;
            }
        } else {
            for (int b = 0; b < NB; ++b) {
                int t = base[b];
                base[b] = run;                         // padded start
                run += (t + QPAD - 1) & ~(QPAD - 1);   // pad to multiple of 4
            }
            // k_start (exclusive prefix of counts) — matches K block's layout
            int krun = 0;
            for (int b = 0; b < NB; ++b) {
                kst[b] = krun;
                krun += kcnt[b];
            }
        }
    }
    __syncthreads();

    // stable placement: slot = bucket_start + within-bucket offset
    if (which) {
        int* blist = k_list + bh * S_LEN;
#pragma unroll
        for (int i = 0; i < 8; ++i) {
            int b   = myb[i];
            int ofs = base[b] + hist[tid][b];
            hist[tid][b]++;
            blist[ofs] = tid * 8 + i;
        }
    } else {
#pragma unroll
        for (int i = 0; i < 8; ++i) {
            int b   = myb[i];
            int ofs = base[b] + hist[tid][b];
            hist[tid][b]++;
            qlist[ofs] = (tid * 8 + i) | (b << 16);
        }
        __syncthreads();
        // emit per-wave-group descriptors
        for (int g = tid; g < NGRP; g += 256) {
            const int e0 = qlist[4 * g];
            int4 dq;
            int  dk = 0;
            if (e0 < 0) {
                dq = int4{-1, -1, -1, -1};
            } else {
                const int b  = e0 >> 16;
                const int e1 = qlist[4 * g + 1];
                const int e2 = qlist[4 * g + 2];
                const int e3 = qlist[4 * g + 3];
                dq.x = e0 & 0xFFFF;
                dq.y = e1 < 0 ? -1 : (e1 & 0xFFFF);
                dq.z = e2 < 0 ? -1 : (e2 & 0xFFFF);
                dq.w = e3 < 0 ? -1 : (e3 & 0xFFFF);
                dk   = kst[b] | (kcnt[b] << 16);
            }
            desc_q[bh * NGRP + g] = dq;
            desc_k[bh * NGRP + g] = dk;
        }
    }
}

// ---- Phase 3: wave per 4 same-bucket queries, 32-key chunks, half-wave D-split.
__global__ __launch_bounds__(256, 6) void lsh_attn_d(const float* __restrict__ Q,
                                                     const float* __restrict__ K,
                                                     const float* __restrict__ V,
                                                     const int4* __restrict__ desc_q,
                                                     const int* __restrict__ desc_k,
                                                     const int* __restrict__ k_list,
                                                     float* __restrict__ out) {
    __shared__ float qlds[4][QPAD][64];   // staged Q rows, per wave
    __shared__ float wbuf[4][QPAD][KCH];  // exp weights, per wave
    __shared__ int   kbuf[4][KCH];        // key indices, per wave

    const int wv   = threadIdx.x >> 6;
    const int lane = threadIdx.x & 63;
    const int h    = lane >> 5;           // dim-half / query-pair owner
    const int kk   = lane & 31;           // key slot within chunk
    const int bh   = blockIdx.y;
    const int grp  = blockIdx.x * 4 + wv; // < NGRP by construction

    const int4 dqv = desc_q[bh * NGRP + grp];
    const int q0 = __builtin_amdgcn_readfirstlane(dqv.x);
    if (q0 < 0) return;                   // all-sentinel group
    const int e1 = __builtin_amdgcn_readfirstlane(dqv.y);
    const int e2 = __builtin_amdgcn_readfirstlane(dqv.z);
    const int e3 = __builtin_amdgcn_readfirstlane(dqv.w);
    const int dk = __builtin_amdgcn_readfirstlane(desc_k[bh * NGRP + grp]);
    const int ks = dk & 0xFFFF;
    const int nk = dk >> 16;

    const bool v1 = e1 >= 0, v2 = e2 >= 0, v3 = e3 >= 0;
    const int q1 = v1 ? e1 : q0;
    const int q2 = v2 ? e2 : q0;
    const int q3 = v3 ? e3 : q0;

    float* outb = out + (size_t)bh * S_LEN * D;
    if (nk == 0) {   // empty key bucket -> zero rows
        outb[(size_t)q0 * D + lane] = 0.0f;
        if (v1) outb[(size_t)q1 * D + lane] = 0.0f;
        if (v2) outb[(size_t)q2 * D + lane] = 0.0f;
        if (v3) outb[(size_t)q3 * D + lane] = 0.0f;
        return;
    }

    const int* kl   = k_list + bh * S_LEN + ks;
    const float* Kb = K + (size_t)bh * S_LEN * D;
    const float* Vb = V + (size_t)bh * S_LEN * D;
    const float* Qb = Q + (size_t)bh * S_LEN * D;

    // stage the 4 Q rows into per-wave LDS (coalesced; same-wave RAW is ordered)
    qlds[wv][0][lane] = Qb[(size_t)q0 * D + lane];
    qlds[wv][1][lane] = Qb[(size_t)q1 * D + lane];
    qlds[wv][2][lane] = Qb[(size_t)q2 * D + lane];
    qlds[wv][3][lane] = Qb[(size_t)q3 * D + lane];

    float l0 = 0.f, l1 = 0.f;             // this lane's 2 owned queries (2h, 2h+1)
    float acc[QPAD] = {0.f, 0.f, 0.f, 0.f};

    for (int c = 0; c * KCH < nk; ++c) {
        const int cnk  = min(KCH, nk - c * KCH);
        const int kidx = kl[c * KCH + min(kk, cnk - 1)];    // coalesced, clamped
        const float* krow = Kb + (size_t)kidx * D + h * 32; // this lane's dim-half

        // ---- partial scores over dim-half h for ALL 4 queries at key kk
        float s0 = 0.f, s1 = 0.f, s2 = 0.f, s3 = 0.f;
#pragma unroll
        for (int i = 0; i < 8; ++i) {
            const float4 kv = *(const float4*)(krow + i * 4);               // gather (half-row)
            const float4 qa = *(const float4*)&qlds[wv][0][h * 32 + i * 4]; // broadcast
            const float4 qb = *(const float4*)&qlds[wv][1][h * 32 + i * 4];
            const float4 qc = *(const float4*)&qlds[wv][2][h * 32 + i * 4];
            const float4 qd = *(const float4*)&qlds[wv][3][h * 32 + i * 4];
            s0 += qa.x * kv.x + qa.y * kv.y + qa.z * kv.z + qa.w * kv.w;
            s1 += qb.x * kv.x + qb.y * kv.y + qb.z * kv.z + qb.w * kv.w;
            s2 += qc.x * kv.x + qc.y * kv.y + qc.z * kv.z + qc.w * kv.w;
            s3 += qd.x * kv.x + qd.y * kv.y + qd.z * kv.z + qd.w * kv.w;
        }
        // combine the two dim-halves (same key kk lives in lanes kk and kk+32)
        s0 += __shfl_xor(s0, 32, 64);
        s1 += __shfl_xor(s1, 32, 64);
        s2 += __shfl_xor(s2, 32, 64);
        s3 += __shfl_xor(s3, 32, 64);

        // ---- each half owns 2 queries: exp + linear l accumulation
        const bool kvalid = kk < cnk;
        const float sa = h ? s2 : s0;
        const float sb = h ? s3 : s1;
        const float ea = kvalid ? __expf(sa * 0.125f) : 0.f;
        const float eb = kvalid ? __expf(sb * 0.125f) : 0.f;
        l0 += ea;
        l1 += eb;
        wbuf[wv][2 * h + 0][kk] = ea;
        wbuf[wv][2 * h + 1][kk] = eb;
        if (h == 0) kbuf[wv][kk] = kidx;
        // same-wave LDS RAW: compiler inserts lgkmcnt wait

        // ---- PV: lane = dim; V rows shared by 4 queries
        const int ng = (cnk + 3) >> 2;
        for (int g = 0; g < ng; ++g) {
            const int4 kx = *(const int4*)&kbuf[wv][g * 4];
            const float vx = Vb[(size_t)kx.x * D + lane];
            const float vy = Vb[(size_t)kx.y * D + lane];
            const float vz = Vb[(size_t)kx.z * D + lane];
            const float vw = Vb[(size_t)kx.w * D + lane];
            const float4 eA = *(const float4*)&wbuf[wv][0][g * 4];
            const float4 eB = *(const float4*)&wbuf[wv][1][g * 4];
            const float4 eC = *(const float4*)&wbuf[wv][2][g * 4];
            const float4 eD = *(const float4*)&wbuf[wv][3][g * 4];
            acc[0] += eA.x * vx + eA.y * vy + eA.z * vz + eA.w * vw;
            acc[1] += eB.x * vx + eB.y * vy + eB.z * vz + eB.w * vw;
            acc[2] += eC.x * vx + eC.y * vy + eC.z * vz + eC.w * vw;
            acc[3] += eD.x * vx + eD.y * vy + eD.z * vz + eD.w * vw;
        }
    }

    // reduce l within each 32-lane half (owned queries), then swap halves
#pragma unroll
    for (int off = 16; off >= 1; off >>= 1) {
        l0 += __shfl_xor(l0, off, 64);
        l1 += __shfl_xor(l1, off, 64);
    }
    const float o0 = __shfl_xor(l0, 32, 64);
    const float o1 = __shfl_xor(l1, 32, 64);
    const float lq0 = h ? o0 : l0;
    const float lq1 = h ? o1 : l1;
    const float lq2 = h ? l0 : o0;
    const float lq3 = h ? l1 : o1;

    const float inv6 = 1.0f / 6.0f;
    outb[(size_t)q0 * D + lane] = acc[0] / (lq0 + 1e-8f) * inv6;
    if (v1) outb[(size_t)q1 * D + lane] = acc[1] / (lq1 + 1e-8f) * inv6;
    if (v2) outb[(size_t)q2 * D + lane] = acc[2] / (lq2 + 1e-8f) * inv6;
    if (v3) outb[(size_t)q3 * D + lane] = acc[3] / (lq3 + 1e-8f) * inv6;
}

extern "C" void kernel_launch(void* const* d_in, const int* in_sizes, int n_in,
                              void* d_out, int out_size, void* d_ws, size_t ws_size,
                              hipStream_t stream) {
    const float* Q   = (const float*)d_in[0];
    const float* K   = (const float*)d_in[1];
    const float* V   = (const float*)d_in[2];
    const float* rot = (const float*)d_in[3];
    float* out = (float*)d_out;

    char* ws = (char*)d_ws;
    int* q_buckets = (int*)(ws);              // 128 KB
    int* k_buckets = (int*)(ws + 131072);     // 128 KB
    int* k_list    = (int*)(ws + 262144);     // 128 KB
    int4* desc_q   = (int4*)(ws + 393216);    // 16*560*16 = 140 KB
    int* desc_k    = (int*)(ws + 536576);     // 16*560*4 = 35 KB

    lsh_buckets2<<<2 * BH * S_LEN / 4, 256, 0, stream>>>(Q, K, rot, q_buckets, k_buckets);
    lsh_build_desc<<<32, 256, 0, stream>>>(q_buckets, k_buckets, k_list, desc_q, desc_k);
    // 560 wave-groups per bh, 4 waves/block -> 140 blocks x 16 bh
    lsh_attn_d<<<dim3(NGRP / 4, BH), 256, 0, stream>>>(Q, K, V, desc_q, desc_k, k_list, out);
}

// Round 9
// 77.108 us; speedup vs baseline: 2.0278x; 2.0278x over previous
//
#include <hip/hip_runtime.h>
#include <math.h>

// LSH attention: B=2, H=8, S=2048, D=64, 6 bits -> 64 buckets, exact-match.
// Phase 1: bucket codes for Q and K (fused, sign of X.rot)
// Phase 2: one dispatch, 32 blocks:
//          K-blocks: stable counting sort -> k_list (segmented parallel scan)
//          Q-blocks: same sort (LDS only) + k-bucket counts -> per-wave-group
//          descriptors {q0..q3},{ks|nk<<16}
// Phase 3: wave per 4 same-bucket queries; 2 uniform descriptor loads; 32-key
//          chunks, half-wave D-split scores with kv[8]-resident K half-row
//          (bounded VGPR, batched gather); no-max softmax; lane=dim PV.

constexpr int S_LEN = 2048;
constexpr int D = 64;
constexpr int NHASH = 6;
constexpr int BH = 16;     // B*H
constexpr int NB = 64;     // 2^NHASH
constexpr int QPAD = 4;    // queries per wave
constexpr int PADQ = S_LEN + (QPAD - 1) * NB;   // 2240
constexpr int NGRP = PADQ / QPAD;               // 560 wave-groups per bh
constexpr int KCH = 32;    // key-chunk width (matches ~32-key buckets)

// ---- Phase 1: bucket codes for Q and K in one dispatch. One wave per vector.
__global__ __launch_bounds__(256) void lsh_buckets2(const float* __restrict__ Q,
                                                    const float* __restrict__ K,
                                                    const float* __restrict__ rot,
                                                    int* __restrict__ qb,
                                                    int* __restrict__ kb) {
    const int gw   = (blockIdx.x * 256 + threadIdx.x) >> 6;
    const int lane = threadIdx.x & 63;
    const bool isK = gw >= BH * S_LEN;
    const int wid  = isK ? gw - BH * S_LEN : gw;
    const float* X = isK ? K : Q;
    int* dst       = isK ? kb : qb;
    const int h    = (wid >> 11) & 7;

    const float x  = X[(size_t)wid * D + lane];
    const float* r = rot + (size_t)h * NHASH * D + lane;
    float p0 = x * r[0 * D], p1 = x * r[1 * D], p2 = x * r[2 * D];
    float p3 = x * r[3 * D], p4 = x * r[4 * D], p5 = x * r[5 * D];
#pragma unroll
    for (int off = 32; off >= 1; off >>= 1) {
        p0 += __shfl_xor(p0, off, 64);
        p1 += __shfl_xor(p1, off, 64);
        p2 += __shfl_xor(p2, off, 64);
        p3 += __shfl_xor(p3, off, 64);
        p4 += __shfl_xor(p4, off, 64);
        p5 += __shfl_xor(p5, off, 64);
    }
    int bucket = (p0 > 0.f ? 1 : 0) | (p1 > 0.f ? 2 : 0) | (p2 > 0.f ? 4 : 0) |
                 (p3 > 0.f ? 8 : 0) | (p4 > 0.f ? 16 : 0) | (p5 > 0.f ? 32 : 0);
    if (lane == 0) dst[wid] = bucket;
}

// ---- Phase 2: one block per (which, bh). which: 0=Q(descriptors) 1=K(list)
__global__ __launch_bounds__(256) void lsh_build_desc(const int* __restrict__ qbuckets,
                                                      const int* __restrict__ kbuckets,
                                                      int* __restrict__ k_list,
                                                      int4* __restrict__ desc_q,
                                                      int* __restrict__ desc_k) {
    __shared__ unsigned short hist[256][NB + 1];
    __shared__ int base[NB + 1];
    __shared__ int seg[NB][4];
    __shared__ int qlist[PADQ];        // Q side only
    __shared__ int kcnt[NB], kst[NB];  // Q side only
    const int which = blockIdx.x >> 4;   // 0 = Q, 1 = K
    const int bh    = blockIdx.x & 15;
    const int tid   = threadIdx.x;
    const int* src  = (which ? kbuckets : qbuckets) + bh * S_LEN;

    for (int b = 0; b <= NB; ++b) hist[tid][b] = 0;
    if (!which) {
        for (int t = tid; t < PADQ; t += 256) qlist[t] = -1;
        if (tid < NB) kcnt[tid] = 0;
        __syncthreads();   // kcnt zeroed before LDS atomics
        const int* kb = kbuckets + bh * S_LEN;
#pragma unroll
        for (int i = 0; i < 8; ++i)
            atomicAdd(&kcnt[kb[tid * 8 + i]], 1);
    }

    int myb[8];
#pragma unroll
    for (int i = 0; i < 8; ++i) {
        int b = src[tid * 8 + i];
        myb[i] = b;
        hist[tid][b]++;
    }
    __syncthreads();

    // segmented per-bucket prefix over the 256 chunks (4 segments x 64 chunks).
    // Phase A: segment sums. tid = b*4 + s
    {
        const int b = tid >> 2, s = tid & 3;
        int sum = 0;
        for (int c = s * 64; c < s * 64 + 64; ++c) sum += hist[c][b];
        seg[b][s] = sum;
    }
    __syncthreads();
    // Phase B: scan the 4 segments per bucket; bucket totals -> base[b]
    if (tid < NB) {
        int run = 0;
#pragma unroll
        for (int s = 0; s < 4; ++s) {
            int t = seg[tid][s];
            seg[tid][s] = run;
            run += t;
        }
        base[tid] = run;   // bucket count
    }
    __syncthreads();

    if (tid == 0) {
        int run = 0;
        if (which) {
            for (int b = 0; b < NB; ++b) {
                int t = base[b];
                base[b] = run;
                run += t;
            }
        } else {
            for (int b = 0; b < NB; ++b) {
                int t = base[b];
                base[b] = run;                         // padded start
                run += (t + QPAD - 1) & ~(QPAD - 1);   // pad to multiple of 4
            }
            // k_start (exclusive prefix of counts) — matches K block's layout
            int krun = 0;
            for (int b = 0; b < NB; ++b) {
                kst[b] = krun;
                krun += kcnt[b];
            }
        }
    }
    __syncthreads();

    // Phase C: within-segment scan, leaves within-bucket offsets in hist
    {
        const int b = tid >> 2, s = tid & 3;
        int run = seg[b][s];
        for (int c = s * 64; c < s * 64 + 64; ++c) {
            int t = hist[c][b];
            hist[c][b] = (unsigned short)run;
            run += t;
        }
    }
    __syncthreads();

    // stable placement: slot = bucket_start + within-bucket offset
    if (which) {
        int* blist = k_list + bh * S_LEN;
#pragma unroll
        for (int i = 0; i < 8; ++i) {
            int b   = myb[i];
            int ofs = base[b] + hist[tid][b];
            hist[tid][b]++;
            blist[ofs] = tid * 8 + i;
        }
    } else {
#pragma unroll
        for (int i = 0; i < 8; ++i) {
            int b   = myb[i];
            int ofs = base[b] + hist[tid][b];
            hist[tid][b]++;
            qlist[ofs] = (tid * 8 + i) | (b << 16);
        }
        __syncthreads();
        // emit per-wave-group descriptors
        for (int g = tid; g < NGRP; g += 256) {
            const int e0 = qlist[4 * g];
            int4 dq;
            int  dk = 0;
            if (e0 < 0) {
                dq = int4{-1, -1, -1, -1};
            } else {
                const int b  = e0 >> 16;
                const int e1 = qlist[4 * g + 1];
                const int e2 = qlist[4 * g + 2];
                const int e3 = qlist[4 * g + 3];
                dq.x = e0 & 0xFFFF;
                dq.y = e1 < 0 ? -1 : (e1 & 0xFFFF);
                dq.z = e2 < 0 ? -1 : (e2 & 0xFFFF);
                dq.w = e3 < 0 ? -1 : (e3 & 0xFFFF);
                dk   = kst[b] | (kcnt[b] << 16);
            }
            desc_q[bh * NGRP + g] = dq;
            desc_k[bh * NGRP + g] = dk;
        }
    }
}

// ---- Phase 3: wave per 4 same-bucket queries, 32-key chunks, half-wave D-split.
__global__ __launch_bounds__(256) void lsh_attn_d(const float* __restrict__ Q,
                                                  const float* __restrict__ K,
                                                  const float* __restrict__ V,
                                                  const int4* __restrict__ desc_q,
                                                  const int* __restrict__ desc_k,
                                                  const int* __restrict__ k_list,
                                                  float* __restrict__ out) {
    __shared__ float qlds[4][QPAD][64];   // staged Q rows, per wave
    __shared__ float wbuf[4][QPAD][KCH];  // exp weights, per wave
    __shared__ int   kbuf[4][KCH];        // key indices, per wave

    const int wv   = threadIdx.x >> 6;
    const int lane = threadIdx.x & 63;
    const int h    = lane >> 5;           // dim-half / query-pair owner
    const int kk   = lane & 31;           // key slot within chunk
    const int bh   = blockIdx.y;
    const int grp  = blockIdx.x * 4 + wv; // < NGRP by construction

    const int4 dqv = desc_q[bh * NGRP + grp];
    const int q0 = __builtin_amdgcn_readfirstlane(dqv.x);
    if (q0 < 0) return;                   // all-sentinel group
    const int e1 = __builtin_amdgcn_readfirstlane(dqv.y);
    const int e2 = __builtin_amdgcn_readfirstlane(dqv.z);
    const int e3 = __builtin_amdgcn_readfirstlane(dqv.w);
    const int dk = __builtin_amdgcn_readfirstlane(desc_k[bh * NGRP + grp]);
    const int ks = dk & 0xFFFF;
    const int nk = dk >> 16;

    const bool v1 = e1 >= 0, v2 = e2 >= 0, v3 = e3 >= 0;
    const int q1 = v1 ? e1 : q0;
    const int q2 = v2 ? e2 : q0;
    const int q3 = v3 ? e3 : q0;

    float* outb = out + (size_t)bh * S_LEN * D;
    if (nk == 0) {   // empty key bucket -> zero rows
        outb[(size_t)q0 * D + lane] = 0.0f;
        if (v1) outb[(size_t)q1 * D + lane] = 0.0f;
        if (v2) outb[(size_t)q2 * D + lane] = 0.0f;
        if (v3) outb[(size_t)q3 * D + lane] = 0.0f;
        return;
    }

    const int* kl   = k_list + bh * S_LEN + ks;
    const float* Kb = K + (size_t)bh * S_LEN * D;
    const float* Vb = V + (size_t)bh * S_LEN * D;
    const float* Qb = Q + (size_t)bh * S_LEN * D;

    // stage the 4 Q rows into per-wave LDS (coalesced; same-wave RAW is ordered)
    qlds[wv][0][lane] = Qb[(size_t)q0 * D + lane];
    qlds[wv][1][lane] = Qb[(size_t)q1 * D + lane];
    qlds[wv][2][lane] = Qb[(size_t)q2 * D + lane];
    qlds[wv][3][lane] = Qb[(size_t)q3 * D + lane];

    float l0 = 0.f, l1 = 0.f;             // this lane's 2 owned queries (2h, 2h+1)
    float acc[QPAD] = {0.f, 0.f, 0.f, 0.f};

    for (int c = 0; c * KCH < nk; ++c) {
        const int cnk  = min(KCH, nk - c * KCH);
        const int kidx = kl[c * KCH + min(kk, cnk - 1)];    // coalesced, clamped
        const float* krow = Kb + (size_t)kidx * D + h * 32; // this lane's dim-half

        // ---- K half-row resident in registers: 8 gathers issued back-to-back
        float4 kv[8];
#pragma unroll
        for (int i = 0; i < 8; ++i) kv[i] = *(const float4*)(krow + i * 4);

        // ---- partial scores over dim-half h for ALL 4 queries at key kk
        // (query-outer / dim-inner keeps one live Q register stream)
        float s[QPAD];
#pragma unroll
        for (int j = 0; j < QPAD; ++j) {
            const float* qj = &qlds[wv][j][h * 32];
            float sj = 0.f;
#pragma unroll
            for (int i = 0; i < 8; ++i) {
                const float4 qv = *(const float4*)(qj + i * 4);   // LDS broadcast
                sj += qv.x * kv[i].x + qv.y * kv[i].y + qv.z * kv[i].z + qv.w * kv[i].w;
            }
            s[j] = sj;
        }
        // combine the two dim-halves (same key kk lives in lanes kk and kk+32)
        s[0] += __shfl_xor(s[0], 32, 64);
        s[1] += __shfl_xor(s[1], 32, 64);
        s[2] += __shfl_xor(s[2], 32, 64);
        s[3] += __shfl_xor(s[3], 32, 64);

        // ---- each half owns 2 queries: exp + linear l accumulation
        const bool kvalid = kk < cnk;
        const float sa = h ? s[2] : s[0];
        const float sb = h ? s[3] : s[1];
        const float ea = kvalid ? __expf(sa * 0.125f) : 0.f;
        const float eb = kvalid ? __expf(sb * 0.125f) : 0.f;
        l0 += ea;
        l1 += eb;
        wbuf[wv][2 * h + 0][kk] = ea;
        wbuf[wv][2 * h + 1][kk] = eb;
        if (h == 0) kbuf[wv][kk] = kidx;
        // same-wave LDS RAW: compiler inserts lgkmcnt wait

        // ---- PV: lane = dim; V rows shared by 4 queries
        const int ng = (cnk + 3) >> 2;
        for (int g = 0; g < ng; ++g) {
            const int4 kx = *(const int4*)&kbuf[wv][g * 4];
            const float vx = Vb[(size_t)kx.x * D + lane];
            const float vy = Vb[(size_t)kx.y * D + lane];
            const float vz = Vb[(size_t)kx.z * D + lane];
            const float vw = Vb[(size_t)kx.w * D + lane];
            const float4 eA = *(const float4*)&wbuf[wv][0][g * 4];
            const float4 eB = *(const float4*)&wbuf[wv][1][g * 4];
            const float4 eC = *(const float4*)&wbuf[wv][2][g * 4];
            const float4 eD = *(const float4*)&wbuf[wv][3][g * 4];
            acc[0] += eA.x * vx + eA.y * vy + eA.z * vz + eA.w * vw;
            acc[1] += eB.x * vx + eB.y * vy + eB.z * vz + eB.w * vw;
            acc[2] += eC.x * vx + eC.y * vy + eC.z * vz + eC.w * vw;
            acc[3] += eD.x * vx + eD.y * vy + eD.z * vz + eD.w * vw;
        }
    }

    // reduce l within each 32-lane half (owned queries), then swap halves
#pragma unroll
    for (int off = 16; off >= 1; off >>= 1) {
        l0 += __shfl_xor(l0, off, 64);
        l1 += __shfl_xor(l1, off, 64);
    }
    const float o0 = __shfl_xor(l0, 32, 64);
    const float o1 = __shfl_xor(l1, 32, 64);
    const float lq0 = h ? o0 : l0;
    const float lq1 = h ? o1 : l1;
    const float lq2 = h ? l0 : o0;
    const float lq3 = h ? l1 : o1;

    const float inv6 = 1.0f / 6.0f;
    outb[(size_t)q0 * D + lane] = acc[0] / (lq0 + 1e-8f) * inv6;
    if (v1) outb[(size_t)q1 * D + lane] = acc[1] / (lq1 + 1e-8f) * inv6;
    if (v2) outb[(size_t)q2 * D + lane] = acc[2] / (lq2 + 1e-8f) * inv6;
    if (v3) outb[(size_t)q3 * D + lane] = acc[3] / (lq3 + 1e-8f) * inv6;
}

extern "C" void kernel_launch(void* const* d_in, const int* in_sizes, int n_in,
                              void* d_out, int out_size, void* d_ws, size_t ws_size,
                              hipStream_t stream) {
    const float* Q   = (const float*)d_in[0];
    const float* K   = (const float*)d_in[1];
    const float* V   = (const float*)d_in[2];
    const float* rot = (const float*)d_in[3];
    float* out = (float*)d_out;

    char* ws = (char*)d_ws;
    int* q_buckets = (int*)(ws);              // 128 KB
    int* k_buckets = (int*)(ws + 131072);     // 128 KB
    int* k_list    = (int*)(ws + 262144);     // 128 KB
    int4* desc_q   = (int4*)(ws + 393216);    // 16*560*16 = 140 KB
    int* desc_k    = (int*)(ws + 536576);     // 16*560*4 = 35 KB

    lsh_buckets2<<<2 * BH * S_LEN / 4, 256, 0, stream>>>(Q, K, rot, q_buckets, k_buckets);
    lsh_build_desc<<<32, 256, 0, stream>>>(q_buckets, k_buckets, k_list, desc_q, desc_k);
    // 560 wave-groups per bh, 4 waves/block -> 140 blocks x 16 bh
    lsh_attn_d<<<dim3(NGRP / 4, BH), 256, 0, stream>>>(Q, K, V, desc_q, desc_k, k_list, out);
}